// Round 13
// baseline (27.969 us; speedup 1.0000x reference)
//
#include <hip/hip_runtime.h>
#include <math.h>

#define NB 32
#define KK 2
#define PP 256
#define NCLOUD 8192
#define NNODES 512   // K*P
#define NCOEF 163840 // B*K*P*COEF_D
#define NCHUNK 16                 // surf chunks per batch (512 pts each)
#define NSURF (NB * NCHUNK)       // 512
#define CHAM0 512
#define NBLK 897

typedef float v2f __attribute__((ext_vector_type(2)));
typedef float v4f __attribute__((ext_vector_type(4)));

// ws float slot layout (all written every call; no memset, no ws atomics):
//   [0,256)   sep per chamfer quarter-block (8 per batch)
//   [256,320) cov per (b,k)
//   [320,384) reg per block
//   [384,386) joint cosv/locv
//   [512, 512+256*512)      pchf: per quarter-block {fwd[256]|bwd[256]} min-d2
//   [131584, 131584+262144) partial surf min-g per (b,chunk,node)
#define SL_SEP 0
#define SL_COV 256
#define SL_REG 320
#define SL_JNT 384
#define PCHF 512
#define PART0 131584

__device__ inline float waveSum(float v) {
#pragma unroll
  for (int o = 32; o > 0; o >>= 1) v += __shfl_down(v, o);
  return v;
}
__device__ inline float waveMax(float v) {
#pragma unroll
  for (int o = 32; o > 0; o >>= 1) v = fmaxf(v, __shfl_down(v, o));
  return v;
}
__device__ inline float waveMin(float v) {
#pragma unroll
  for (int o = 32; o > 0; o >>= 1) v = fminf(v, __shfl_down(v, o));
  return v;
}
__device__ inline float smooth_l1(float d) {
  d = fabsf(d);
  return d < 0.1f ? 5.0f * d * d : d - 0.05f;
}

// Grid: [0,512) surf: b=bid>>4, chunk c=bid&15 (512 pts, pair-SoA LDS, packed math)
//       [512,768) chamfer quarters: u=bid-512, bk=u>>2, h=u&3 (wave owns 16 j's)
//       [768,832) cov | [832,896) reg | 896 joint (also zeroes out[0])
__global__ __launch_bounds__(256) void mega_kernel(
    const float* __restrict__ coefs,
    const float* __restrict__ preds,
    const float* __restrict__ nodes,
    const float* __restrict__ cloud,
    const int* __restrict__ cls,
    const float* __restrict__ pjl, const float* __restrict__ pja,
    const float* __restrict__ gjl, const float* __restrict__ gja,
    const float* __restrict__ gps,
    float* __restrict__ ws, float* __restrict__ out) {
  const int bid = blockIdx.x;
  const int t = threadIdx.x;
  const int wave = t >> 6, lane = t & 63;
  __shared__ float smem[4096];   // 16 KB, role-dependent
  __shared__ float red[12][4];

  if (bid < CHAM0) {
    // ---------------- surf partial: (b, 512-pt chunk) ----------------
    const int b = bid >> 4;
    const int c = bid & 15;
    const float* cb = cloud + ((size_t)b * NCLOUD + (size_t)c * 512) * 3;
    // pair-SoA staging: pair p: smem[p*8+{0,1}]=x01 {2,3}=y01 {4,5}=z01 {6,7}=h01
#pragma unroll
    for (int g = 0; g < 2; ++g) {
      const int p = g * 256 + t;
      const float qx = cb[3 * p], qy = cb[3 * p + 1], qz = cb[3 * p + 2];
      const float qh = 0.5f * (qx * qx + qy * qy + qz * qz);
      float* base = &smem[(p >> 1) * 8 + (p & 1)];
      base[0] = qx; base[2] = qy; base[4] = qz; base[6] = qh;
    }
    __syncthreads();
    const float* nb = nodes + (size_t)b * NNODES * 3;
    v2f nx2[8], ny2[8], nz2[8];
    float mg[8];
#pragma unroll
    for (int q = 0; q < 8; ++q) {
      const int n = lane + q * 64;
      const float nx = nb[3 * n], ny = nb[3 * n + 1], nz = nb[3 * n + 2];
      nx2[q] = (v2f){-nx, -nx}; ny2[q] = (v2f){-ny, -ny}; nz2[q] = (v2f){-nz, -nz};
      mg[q] = 1e30f;
    }
    const int p0 = wave * 64;   // pair base; wave slice = 64 pairs (128 pts)
#pragma unroll 2
    for (int i = 0; i < 64; ++i) {
      const v4f A = *(const v4f*)&smem[(p0 + i) * 8];       // x01 y01
      const v4f Bv = *(const v4f*)&smem[(p0 + i) * 8 + 4];  // z01 h01
      const v2f X = A.xy, Y = A.zw, Z = Bv.xy, H = Bv.zw;
#pragma unroll
      for (int q = 0; q < 8; ++q) {
        const v2f g = __builtin_elementwise_fma(
            nx2[q], X,
            __builtin_elementwise_fma(
                ny2[q], Y, __builtin_elementwise_fma(nz2[q], Z, H)));
        mg[q] = fminf(fminf(mg[q], g.x), g.y);   // -> v_min3_f32
      }
    }
    // cross-wave min combine (reuse smem), coalesced store of min-g
    __syncthreads();
#pragma unroll
    for (int q = 0; q < 8; ++q) smem[wave * 512 + lane + q * 64] = mg[q];
    __syncthreads();
    float* pout = ws + PART0 + ((size_t)b * NCHUNK + c) * NNODES;
#pragma unroll
    for (int g = 0; g < 2; ++g) {
      const int node = g * 256 + t;
      pout[node] = fminf(fminf(smem[node], smem[512 + node]),
                         fminf(smem[1024 + node], smem[1536 + node]));
    }

  } else if (bid < 768) {
    // -------- chamfer + separation: (b,k) x j-quarter (wave: 16 j's) --------
    const int u = bid - CHAM0;
    const int bk = u >> 2;
    const int h = u & 3;
    float4* sh4 = (float4*)smem;          // [0,2048) floats
    float* shg = smem + 2048;             // [2048,4096)
    const float* pb = preds + (size_t)bk * PP * 3;
    const float* nbp = nodes + (size_t)bk * PP * 3;
    {
      float x = pb[3 * t], y = pb[3 * t + 1], z = pb[3 * t + 2];
      sh4[t] = make_float4(x, y, z, x * x + y * y + z * z);         // preds
      x = nbp[3 * t]; y = nbp[3 * t + 1]; z = nbp[3 * t + 2];
      sh4[256 + t] = make_float4(x, y, z, x * x + y * y + z * z);   // nodes
    }
    __syncthreads();
    float4 ptv[4], ntv[4];
#pragma unroll
    for (int q = 0; q < 4; ++q) {
      ptv[q] = sh4[lane + q * 64];
      ntv[q] = sh4[256 + lane + q * 64];
    }
    const float s0 = gps[bk * 3 + 0], s1 = gps[bk * 3 + 1], s2 = gps[bk * 3 + 2];
    const float thr = sqrtf(s0 * s0 + s1 * s1 + s2 * s2) * 0.125f;
    float g1[4], g2[4], sep = 0.0f;
#pragma unroll
    for (int q = 0; q < 4; ++q) { g1[q] = 1e30f; g2[q] = 1e30f; }
    const int j0 = h * 64 + wave * 16;
#pragma unroll 4
    for (int jj = 0; jj < 16; ++jj) {
      const int j = j0 + jj;
      const float4 pj = sh4[j];
      const float4 nj = sh4[256 + j];
#pragma unroll
      for (int q = 0; q < 4; ++q) {
        float dot = fmaf(ptv[q].x, nj.x, fmaf(ptv[q].y, nj.y, ptv[q].z * nj.z));
        g1[q] = fminf(g1[q], fmaf(-2.0f, dot, nj.w));
        dot = fmaf(ntv[q].x, pj.x, fmaf(ntv[q].y, pj.y, ntv[q].z * pj.z));
        g2[q] = fminf(g2[q], fmaf(-2.0f, dot, pj.w));
        dot = fmaf(ntv[q].x, nj.x, fmaf(ntv[q].y, nj.y, ntv[q].z * nj.z));
        const float d2 = fmaf(-2.0f, dot, ntv[q].w + nj.w);
        const float d = sqrtf(fmaxf(d2, 0.0f));
        if (j != lane + q * 64) sep += fmaxf(thr - d, 0.0f);
      }
    }
    // cross-wave min combine; store per-element partial min-d2 (fwd/bwd)
#pragma unroll
    for (int q = 0; q < 4; ++q) {
      shg[wave * 256 + lane + q * 64] = ptv[q].w + g1[q];
      shg[1024 + wave * 256 + lane + q * 64] = ntv[q].w + g2[q];
    }
    __syncthreads();
    float* pc = ws + PCHF + (size_t)u * 512;
    pc[t] = fminf(fminf(shg[t], shg[256 + t]),
                  fminf(shg[512 + t], shg[768 + t]));
    pc[256 + t] = fminf(fminf(shg[1024 + t], shg[1280 + t]),
                        fminf(shg[1536 + t], shg[1792 + t]));
    sep = waveSum(sep);
    if (lane == 0) red[0][wave] = sep;
    __syncthreads();
    if (t == 0)
      ws[SL_SEP + u] = red[0][0] + red[0][1] + red[0][2] + red[0][3];

  } else if (bid < 832) {
    // ---------------- coverage per (b,k) ----------------
    const int bk = bid - 768;
    const int b = bk >> 1;
    const int k = bk & 1;
    float pmax0 = -1e9f, pmax1 = -1e9f, pmax2 = -1e9f;
    float pmin0 = 1e9f, pmin1 = 1e9f, pmin2 = 1e9f;
    const float* cb = cloud + (size_t)b * NCLOUD * 3;
    const int* lb = cls + (size_t)b * NCLOUD;
    for (int i = t; i < NCLOUD; i += 256) {
      if (lb[i] == k) {
        const float x = cb[i * 3 + 0], y = cb[i * 3 + 1], z = cb[i * 3 + 2];
        pmax0 = fmaxf(pmax0, x); pmax1 = fmaxf(pmax1, y); pmax2 = fmaxf(pmax2, z);
        pmin0 = fminf(pmin0, x); pmin1 = fminf(pmin1, y); pmin2 = fminf(pmin2, z);
      }
    }
    const float* nb = nodes + (size_t)bk * PP * 3;
    const float kx = nb[t * 3 + 0], ky = nb[t * 3 + 1], kz = nb[t * 3 + 2];
    pmax0 = waveMax(pmax0); pmax1 = waveMax(pmax1); pmax2 = waveMax(pmax2);
    pmin0 = waveMin(pmin0); pmin1 = waveMin(pmin1); pmin2 = waveMin(pmin2);
    float kmax0 = waveMax(kx), kmax1 = waveMax(ky), kmax2 = waveMax(kz);
    float kmin0 = waveMin(kx), kmin1 = waveMin(ky), kmin2 = waveMin(kz);
    if (lane == 0) {
      red[0][wave] = pmax0; red[1][wave] = pmax1; red[2][wave] = pmax2;
      red[3][wave] = pmin0; red[4][wave] = pmin1; red[5][wave] = pmin2;
      red[6][wave] = kmax0; red[7][wave] = kmax1; red[8][wave] = kmax2;
      red[9][wave] = kmin0; red[10][wave] = kmin1; red[11][wave] = kmin2;
    }
    __syncthreads();
    if (t == 0) {
      float v[12];
#pragma unroll
      for (int q = 0; q < 12; ++q) {
        if (q < 3 || (q >= 6 && q < 9))
          v[q] = fmaxf(fmaxf(red[q][0], red[q][1]), fmaxf(red[q][2], red[q][3]));
        else
          v[q] = fminf(fminf(red[q][0], red[q][1]), fminf(red[q][2], red[q][3]));
      }
      float s = 0.0f;
#pragma unroll
      for (int c2 = 0; c2 < 3; ++c2)
        s += 0.5f * (smooth_l1(v[6 + c2] - v[0 + c2]) + smooth_l1(v[9 + c2] - v[3 + c2]));
      ws[SL_COV + bk] = s;
    }

  } else if (bid < 896) {
    // ---------------- regularizer ----------------
    const int r = bid - 832;
    const float4* c4 = (const float4*)coefs;
    float v = 0.0f;
    for (int i = r * 256 + t; i < NCOEF / 4; i += 64 * 256) {
      const float4 q = c4[i];
      v += q.x * q.x + q.y * q.y + q.z * q.z + q.w * q.w;
    }
    v = waveSum(v);
    if (lane == 0) red[0][wave] = v;
    __syncthreads();
    if (t == 0)
      ws[SL_REG + r] = red[0][0] + red[0][1] + red[0][2] + red[0][3];

  } else {
    // ---------------- joint (+ zero the output accumulator) ----------------
    float cosv = 0.0f, locv = 0.0f;
    if (t < NB) {
      const float axj = pja[t * 3 + 0], ayj = pja[t * 3 + 1], azj = pja[t * 3 + 2];
      const float gx = gja[t * 3 + 0], gy = gja[t * 3 + 1], gz = gja[t * 3 + 2];
      const float dot = axj * gx + ayj * gy + azj * gz;
      const float na = sqrtf(axj * axj + ayj * ayj + azj * azj);
      const float nbn = sqrtf(gx * gx + gy * gy + gz * gz);
      cosv = dot / fmaxf(na * nbn, 1e-8f);
      const float ux = gx / nbn, uy = gy / nbn, uz = gz / nbn;
      const float px = gjl[t * 3 + 0], py = gjl[t * 3 + 1], pz = gjl[t * 3 + 2];
      const float qx = px + ux, qy = py + uy, qz = pz + uz;
      const float rx = pjl[t * 3 + 0], ry = pjl[t * 3 + 1], rz = pjl[t * 3 + 2];
      const float xx = px - qx, xy = py - qy, xz = pz - qz;
      const float tnum = (rx - qx) * xx + (ry - qy) * xy + (rz - qz) * xz;
      const float tden = xx * xx + xy * xy + xz * xz;
      const float tv = tnum / tden;
      const float vx = tv * xx + (qx - rx);
      const float vy = tv * xy + (qy - ry);
      const float vz = tv * xz + (qz - rz);
      locv = sqrtf(vx * vx + vy * vy + vz * vz);
    }
    cosv = waveSum(cosv);
    locv = waveSum(locv);
    if (t == 0) {
      ws[SL_JNT + 0] = cosv;
      ws[SL_JNT + 1] = locv;
      out[0] = 0.0f;   // accumulator for final1 (kernel boundary => visible)
    }
  }
}

// --- final1 (64 blocks): (b, half) combine surf chunks + chamfer quarters +
//     slot shares; weighted atomicAdd into out[0] ---
__global__ __launch_bounds__(256) void final1_kernel(
    const float* __restrict__ nodes, const float* __restrict__ ws,
    float* __restrict__ out) {
  const int b = blockIdx.x >> 1;
  const int half = blockIdx.x & 1;
  const int t = threadIdx.x;
  const int wave = t >> 6, lane = t & 63;
  const float* partial = ws + PART0;
  const float* nb = nodes + (size_t)b * NNODES * 3;
  // surf: 256 nodes of this half
  const int node = half * 256 + t;
  float m = 1e30f;
#pragma unroll
  for (int c = 0; c < NCHUNK; ++c)
    m = fminf(m, partial[((size_t)b * NCHUNK + c) * NNODES + node]);
  const float x = nb[3 * node], y = nb[3 * node + 1], z = nb[3 * node + 2];
  const float nn = x * x + y * y + z * z;
  float ssum = sqrtf(fmaxf(fmaf(2.0f, m, nn), 1e-12f));
  // chamfer: k = half; min over the 4 quarters of bk
  float csum = 0.0f;
  {
    const int bk = b * KK + half;
    const float* q0 = ws + PCHF + (size_t)(4 * bk + 0) * 512;
    const float* q1 = ws + PCHF + (size_t)(4 * bk + 1) * 512;
    const float* q2 = ws + PCHF + (size_t)(4 * bk + 2) * 512;
    const float* q3 = ws + PCHF + (size_t)(4 * bk + 3) * 512;
    const float fwd = fminf(fminf(q0[t], q1[t]), fminf(q2[t], q3[t]));
    const float bwd = fminf(fminf(q0[256 + t], q1[256 + t]),
                            fminf(q2[256 + t], q3[256 + t]));
    csum = sqrtf(fmaxf(fwd, 1e-12f)) + sqrtf(fmaxf(bwd, 1e-12f));
  }
  ssum = waveSum(ssum);
  csum = waveSum(csum);
  __shared__ float r[2][4];
  if (lane == 0) { r[0][wave] = ssum; r[1][wave] = csum; }
  __syncthreads();
  if (t == 0) {
    const float ssum_t = r[0][0] + r[0][1] + r[0][2] + r[0][3];
    const float csum_t = r[1][0] + r[1][1] + r[1][2] + r[1][3];
    float v = ssum_t * (5.0f / (float)(NB * NNODES)) +
              csum_t * (1.0f / (float)(KK * NB * PP));
    // this block's share: sep 4 quarter slots, cov 1, reg 1
    float sep4 = 0.0f;
#pragma unroll
    for (int q = 0; q < 4; ++q) sep4 += ws[SL_SEP + 8 * b + 4 * half + q];
    v += sep4 * (2.0f / (float)(NB * KK * PP * (PP - 1)));
    v += ws[SL_COV + 2 * b + half] * (1.0f / (float)(NB * KK * 3));
    v += ws[SL_REG + blockIdx.x] * (0.01f / (float)NCOEF);
    if (blockIdx.x == 0) {
      const float axis = 1.0f - ws[SL_JNT + 0] / (float)NB;
      const float loc = ws[SL_JNT + 1] / (float)NB;
      v += loc + 0.5f * axis;
    }
    atomicAdd(out, v);
  }
}

extern "C" void kernel_launch(void* const* d_in, const int* in_sizes, int n_in,
                              void* d_out, int out_size, void* d_ws, size_t ws_size,
                              hipStream_t stream) {
  const float* coefs = (const float*)d_in[0];
  const float* preds = (const float*)d_in[1];
  const float* nodes = (const float*)d_in[2];
  const float* cloud = (const float*)d_in[3];
  const int* cls = (const int*)d_in[4];
  const float* pjl = (const float*)d_in[5];
  const float* pja = (const float*)d_in[6];
  const float* gjl = (const float*)d_in[7];
  const float* gja = (const float*)d_in[8];
  const float* gps = (const float*)d_in[9];
  float* out = (float*)d_out;
  float* ws = (float*)d_ws;

  mega_kernel<<<NBLK, 256, 0, stream>>>(coefs, preds, nodes, cloud, cls,
                                        pjl, pja, gjl, gja, gps, ws, out);
  final1_kernel<<<2 * NB, 256, 0, stream>>>(nodes, ws, out);
}

// Round 14
// 25.235 us; speedup vs baseline: 1.1083x; 1.1083x over previous
//
#include <hip/hip_runtime.h>
#include <math.h>

#define NB 32
#define KK 2
#define PP 256
#define NCLOUD 8192
#define NNODES 512   // K*P
#define NCOEF 163840 // B*K*P*COEF_D
#define NCHUNK 16                 // surf chunks per batch (512 pts each)
#define CHAM0 512
#define NBLK 897

// ws float slot layout (all written every call; no memset, no ws atomics):
//   [0,256)   sep per chamfer quarter-block (8 per batch)
//   [256,320) cov per (b,k)
//   [320,384) reg per block
//   [384,386) joint cosv/locv
//   [512, 512+256*512)      pchf: per quarter-block {fwd[256]|bwd[256]} min-d2
//   [131584, 131584+262144) partial surf min-g per (b,chunk,node)
#define SL_SEP 0
#define SL_COV 256
#define SL_REG 320
#define SL_JNT 384
#define PCHF 512
#define PART0 131584

__device__ inline float waveSum(float v) {
#pragma unroll
  for (int o = 32; o > 0; o >>= 1) v += __shfl_down(v, o);
  return v;
}
__device__ inline float waveMax(float v) {
#pragma unroll
  for (int o = 32; o > 0; o >>= 1) v = fmaxf(v, __shfl_down(v, o));
  return v;
}
__device__ inline float waveMin(float v) {
#pragma unroll
  for (int o = 32; o > 0; o >>= 1) v = fminf(v, __shfl_down(v, o));
  return v;
}
__device__ inline float smooth_l1(float d) {
  d = fabsf(d);
  return d < 0.1f ? 5.0f * d * d : d - 0.05f;
}

// Grid: [0,512) surf: b=bid>>4, chunk c=bid&15 (512 pts, float4/pt LDS — r12 layout)
//       [512,768) chamfer quarters: u=bid-512, bk=u>>2, h=u&3 (wave owns 16 j's)
//       [768,832) cov | [832,896) reg | 896 joint (also zeroes out[0])
__global__ __launch_bounds__(256) void mega_kernel(
    const float* __restrict__ coefs,
    const float* __restrict__ preds,
    const float* __restrict__ nodes,
    const float* __restrict__ cloud,
    const int* __restrict__ cls,
    const float* __restrict__ pjl, const float* __restrict__ pja,
    const float* __restrict__ gjl, const float* __restrict__ gja,
    const float* __restrict__ gps,
    float* __restrict__ ws, float* __restrict__ out) {
  const int bid = blockIdx.x;
  const int t = threadIdx.x;
  const int wave = t >> 6, lane = t & 63;
  __shared__ float4 sh4[512];     // 8 KB
  __shared__ float shg[2048];     // 8 KB (cross-wave combine)
  __shared__ float red[12][4];

  if (bid < CHAM0) {
    // ---------------- surf partial: (b, 512-pt chunk) ----------------
    const int b = bid >> 4;
    const int c = bid & 15;
    const float* cb = cloud + ((size_t)b * NCLOUD + (size_t)c * 512) * 3;
#pragma unroll
    for (int g = 0; g < 2; ++g) {
      const int idx = g * 256 + t;
      const float qx = cb[3 * idx], qy = cb[3 * idx + 1], qz = cb[3 * idx + 2];
      sh4[idx] = make_float4(qx, qy, qz, 0.5f * (qx * qx + qy * qy + qz * qz));
    }
    __syncthreads();
    const float* nb = nodes + (size_t)b * NNODES * 3;
    float nxv[8], nyv[8], nzv[8], mg[8];
#pragma unroll
    for (int q = 0; q < 8; ++q) {
      const int n = lane + q * 64;
      nxv[q] = nb[3 * n]; nyv[q] = nb[3 * n + 1]; nzv[q] = nb[3 * n + 2];
      mg[q] = 1e30f;
    }
    const int p0 = wave * 128;
#pragma unroll 2
    for (int j = 0; j < 128; j += 2) {
      const float4 qa = sh4[p0 + j];
      const float4 qb = sh4[p0 + j + 1];
#pragma unroll
      for (int q = 0; q < 8; ++q) {
        const float ga = fmaf(-nxv[q], qa.x,
                              fmaf(-nyv[q], qa.y, fmaf(-nzv[q], qa.z, qa.w)));
        const float gb = fmaf(-nxv[q], qb.x,
                              fmaf(-nyv[q], qb.y, fmaf(-nzv[q], qb.z, qb.w)));
        mg[q] = fminf(fminf(mg[q], ga), gb);   // -> v_min3_f32
      }
    }
    // cross-wave min combine in LDS, coalesced store of min-g
#pragma unroll
    for (int q = 0; q < 8; ++q)
      shg[wave * 512 + lane + q * 64] = mg[q];
    __syncthreads();
    float* pout = ws + PART0 + ((size_t)b * NCHUNK + c) * NNODES;
#pragma unroll
    for (int g = 0; g < 2; ++g) {
      const int node = g * 256 + t;
      pout[node] = fminf(fminf(shg[node], shg[512 + node]),
                         fminf(shg[1024 + node], shg[1536 + node]));
    }

  } else if (bid < 768) {
    // -------- chamfer + separation: (b,k) x j-quarter (wave: 16 j's) --------
    const int u = bid - CHAM0;
    const int bk = u >> 2;
    const int h = u & 3;
    const float* pb = preds + (size_t)bk * PP * 3;
    const float* nbp = nodes + (size_t)bk * PP * 3;
    {
      float x = pb[3 * t], y = pb[3 * t + 1], z = pb[3 * t + 2];
      sh4[t] = make_float4(x, y, z, x * x + y * y + z * z);         // preds
      x = nbp[3 * t]; y = nbp[3 * t + 1]; z = nbp[3 * t + 2];
      sh4[256 + t] = make_float4(x, y, z, x * x + y * y + z * z);   // nodes
    }
    __syncthreads();
    float4 ptv[4], ntv[4];
#pragma unroll
    for (int q = 0; q < 4; ++q) {
      ptv[q] = sh4[lane + q * 64];
      ntv[q] = sh4[256 + lane + q * 64];
    }
    const float s0 = gps[bk * 3 + 0], s1 = gps[bk * 3 + 1], s2 = gps[bk * 3 + 2];
    const float thr = sqrtf(s0 * s0 + s1 * s1 + s2 * s2) * 0.125f;
    float g1[4], g2[4], sep = 0.0f;
#pragma unroll
    for (int q = 0; q < 4; ++q) { g1[q] = 1e30f; g2[q] = 1e30f; }
    const int j0 = h * 64 + wave * 16;
#pragma unroll 4
    for (int jj = 0; jj < 16; ++jj) {
      const int j = j0 + jj;
      const float4 pj = sh4[j];
      const float4 nj = sh4[256 + j];
#pragma unroll
      for (int q = 0; q < 4; ++q) {
        float dot = fmaf(ptv[q].x, nj.x, fmaf(ptv[q].y, nj.y, ptv[q].z * nj.z));
        g1[q] = fminf(g1[q], fmaf(-2.0f, dot, nj.w));
        dot = fmaf(ntv[q].x, pj.x, fmaf(ntv[q].y, pj.y, ntv[q].z * pj.z));
        g2[q] = fminf(g2[q], fmaf(-2.0f, dot, pj.w));
        dot = fmaf(ntv[q].x, nj.x, fmaf(ntv[q].y, nj.y, ntv[q].z * nj.z));
        const float d2 = fmaf(-2.0f, dot, ntv[q].w + nj.w);
        const float d = sqrtf(fmaxf(d2, 0.0f));
        if (j != lane + q * 64) sep += fmaxf(thr - d, 0.0f);
      }
    }
    // cross-wave min combine; store per-element partial min-d2 (fwd/bwd)
#pragma unroll
    for (int q = 0; q < 4; ++q) {
      shg[wave * 256 + lane + q * 64] = ptv[q].w + g1[q];
      shg[1024 + wave * 256 + lane + q * 64] = ntv[q].w + g2[q];
    }
    __syncthreads();
    float* pc = ws + PCHF + (size_t)u * 512;
    pc[t] = fminf(fminf(shg[t], shg[256 + t]),
                  fminf(shg[512 + t], shg[768 + t]));
    pc[256 + t] = fminf(fminf(shg[1024 + t], shg[1280 + t]),
                        fminf(shg[1536 + t], shg[1792 + t]));
    sep = waveSum(sep);
    if (lane == 0) red[0][wave] = sep;
    __syncthreads();
    if (t == 0)
      ws[SL_SEP + u] = red[0][0] + red[0][1] + red[0][2] + red[0][3];

  } else if (bid < 832) {
    // ---------------- coverage per (b,k) ----------------
    const int bk = bid - 768;
    const int b = bk >> 1;
    const int k = bk & 1;
    float pmax0 = -1e9f, pmax1 = -1e9f, pmax2 = -1e9f;
    float pmin0 = 1e9f, pmin1 = 1e9f, pmin2 = 1e9f;
    const float* cb = cloud + (size_t)b * NCLOUD * 3;
    const int* lb = cls + (size_t)b * NCLOUD;
    for (int i = t; i < NCLOUD; i += 256) {
      if (lb[i] == k) {
        const float x = cb[i * 3 + 0], y = cb[i * 3 + 1], z = cb[i * 3 + 2];
        pmax0 = fmaxf(pmax0, x); pmax1 = fmaxf(pmax1, y); pmax2 = fmaxf(pmax2, z);
        pmin0 = fminf(pmin0, x); pmin1 = fminf(pmin1, y); pmin2 = fminf(pmin2, z);
      }
    }
    const float* nb = nodes + (size_t)bk * PP * 3;
    const float kx = nb[t * 3 + 0], ky = nb[t * 3 + 1], kz = nb[t * 3 + 2];
    pmax0 = waveMax(pmax0); pmax1 = waveMax(pmax1); pmax2 = waveMax(pmax2);
    pmin0 = waveMin(pmin0); pmin1 = waveMin(pmin1); pmin2 = waveMin(pmin2);
    float kmax0 = waveMax(kx), kmax1 = waveMax(ky), kmax2 = waveMax(kz);
    float kmin0 = waveMin(kx), kmin1 = waveMin(ky), kmin2 = waveMin(kz);
    if (lane == 0) {
      red[0][wave] = pmax0; red[1][wave] = pmax1; red[2][wave] = pmax2;
      red[3][wave] = pmin0; red[4][wave] = pmin1; red[5][wave] = pmin2;
      red[6][wave] = kmax0; red[7][wave] = kmax1; red[8][wave] = kmax2;
      red[9][wave] = kmin0; red[10][wave] = kmin1; red[11][wave] = kmin2;
    }
    __syncthreads();
    if (t == 0) {
      float v[12];
#pragma unroll
      for (int q = 0; q < 12; ++q) {
        if (q < 3 || (q >= 6 && q < 9))
          v[q] = fmaxf(fmaxf(red[q][0], red[q][1]), fmaxf(red[q][2], red[q][3]));
        else
          v[q] = fminf(fminf(red[q][0], red[q][1]), fminf(red[q][2], red[q][3]));
      }
      float s = 0.0f;
#pragma unroll
      for (int c2 = 0; c2 < 3; ++c2)
        s += 0.5f * (smooth_l1(v[6 + c2] - v[0 + c2]) + smooth_l1(v[9 + c2] - v[3 + c2]));
      ws[SL_COV + bk] = s;
    }

  } else if (bid < 896) {
    // ---------------- regularizer ----------------
    const int r = bid - 832;
    const float4* c4 = (const float4*)coefs;
    float v = 0.0f;
    for (int i = r * 256 + t; i < NCOEF / 4; i += 64 * 256) {
      const float4 q = c4[i];
      v += q.x * q.x + q.y * q.y + q.z * q.z + q.w * q.w;
    }
    v = waveSum(v);
    if (lane == 0) red[0][wave] = v;
    __syncthreads();
    if (t == 0)
      ws[SL_REG + r] = red[0][0] + red[0][1] + red[0][2] + red[0][3];

  } else {
    // ---------------- joint (+ zero the output accumulator) ----------------
    float cosv = 0.0f, locv = 0.0f;
    if (t < NB) {
      const float axj = pja[t * 3 + 0], ayj = pja[t * 3 + 1], azj = pja[t * 3 + 2];
      const float gx = gja[t * 3 + 0], gy = gja[t * 3 + 1], gz = gja[t * 3 + 2];
      const float dot = axj * gx + ayj * gy + azj * gz;
      const float na = sqrtf(axj * axj + ayj * ayj + azj * azj);
      const float nbn = sqrtf(gx * gx + gy * gy + gz * gz);
      cosv = dot / fmaxf(na * nbn, 1e-8f);
      const float ux = gx / nbn, uy = gy / nbn, uz = gz / nbn;
      const float px = gjl[t * 3 + 0], py = gjl[t * 3 + 1], pz = gjl[t * 3 + 2];
      const float qx = px + ux, qy = py + uy, qz = pz + uz;
      const float rx = pjl[t * 3 + 0], ry = pjl[t * 3 + 1], rz = pjl[t * 3 + 2];
      const float xx = px - qx, xy = py - qy, xz = pz - qz;
      const float tnum = (rx - qx) * xx + (ry - qy) * xy + (rz - qz) * xz;
      const float tden = xx * xx + xy * xy + xz * xz;
      const float tv = tnum / tden;
      const float vx = tv * xx + (qx - rx);
      const float vy = tv * xy + (qy - ry);
      const float vz = tv * xz + (qz - rz);
      locv = sqrtf(vx * vx + vy * vy + vz * vz);
    }
    cosv = waveSum(cosv);
    locv = waveSum(locv);
    if (t == 0) {
      ws[SL_JNT + 0] = cosv;
      ws[SL_JNT + 1] = locv;
      out[0] = 0.0f;   // accumulator for final1 (kernel boundary => visible)
    }
  }
}

// --- final1 (64 blocks): (b, half) combine surf chunks + chamfer quarters +
//     slot shares; weighted atomicAdd into out[0] ---
__global__ __launch_bounds__(256) void final1_kernel(
    const float* __restrict__ nodes, const float* __restrict__ ws,
    float* __restrict__ out) {
  const int b = blockIdx.x >> 1;
  const int half = blockIdx.x & 1;
  const int t = threadIdx.x;
  const int wave = t >> 6, lane = t & 63;
  const float* partial = ws + PART0;
  const float* nb = nodes + (size_t)b * NNODES * 3;
  // surf: 256 nodes of this half
  const int node = half * 256 + t;
  float m = 1e30f;
#pragma unroll
  for (int c = 0; c < NCHUNK; ++c)
    m = fminf(m, partial[((size_t)b * NCHUNK + c) * NNODES + node]);
  const float x = nb[3 * node], y = nb[3 * node + 1], z = nb[3 * node + 2];
  const float nn = x * x + y * y + z * z;
  float ssum = sqrtf(fmaxf(fmaf(2.0f, m, nn), 1e-12f));
  // chamfer: k = half; min over the 4 quarters of bk
  float csum = 0.0f;
  {
    const int bk = b * KK + half;
    const float* q0 = ws + PCHF + (size_t)(4 * bk + 0) * 512;
    const float* q1 = ws + PCHF + (size_t)(4 * bk + 1) * 512;
    const float* q2 = ws + PCHF + (size_t)(4 * bk + 2) * 512;
    const float* q3 = ws + PCHF + (size_t)(4 * bk + 3) * 512;
    const float fwd = fminf(fminf(q0[t], q1[t]), fminf(q2[t], q3[t]));
    const float bwd = fminf(fminf(q0[256 + t], q1[256 + t]),
                            fminf(q2[256 + t], q3[256 + t]));
    csum = sqrtf(fmaxf(fwd, 1e-12f)) + sqrtf(fmaxf(bwd, 1e-12f));
  }
  ssum = waveSum(ssum);
  csum = waveSum(csum);
  __shared__ float r[2][4];
  if (lane == 0) { r[0][wave] = ssum; r[1][wave] = csum; }
  __syncthreads();
  if (t == 0) {
    const float ssum_t = r[0][0] + r[0][1] + r[0][2] + r[0][3];
    const float csum_t = r[1][0] + r[1][1] + r[1][2] + r[1][3];
    float v = ssum_t * (5.0f / (float)(NB * NNODES)) +
              csum_t * (1.0f / (float)(KK * NB * PP));
    float sep4 = 0.0f;
#pragma unroll
    for (int q = 0; q < 4; ++q) sep4 += ws[SL_SEP + 8 * b + 4 * half + q];
    v += sep4 * (2.0f / (float)(NB * KK * PP * (PP - 1)));
    v += ws[SL_COV + 2 * b + half] * (1.0f / (float)(NB * KK * 3));
    v += ws[SL_REG + blockIdx.x] * (0.01f / (float)NCOEF);
    if (blockIdx.x == 0) {
      const float axis = 1.0f - ws[SL_JNT + 0] / (float)NB;
      const float loc = ws[SL_JNT + 1] / (float)NB;
      v += loc + 0.5f * axis;
    }
    atomicAdd(out, v);
  }
}

extern "C" void kernel_launch(void* const* d_in, const int* in_sizes, int n_in,
                              void* d_out, int out_size, void* d_ws, size_t ws_size,
                              hipStream_t stream) {
  const float* coefs = (const float*)d_in[0];
  const float* preds = (const float*)d_in[1];
  const float* nodes = (const float*)d_in[2];
  const float* cloud = (const float*)d_in[3];
  const int* cls = (const int*)d_in[4];
  const float* pjl = (const float*)d_in[5];
  const float* pja = (const float*)d_in[6];
  const float* gjl = (const float*)d_in[7];
  const float* gja = (const float*)d_in[8];
  const float* gps = (const float*)d_in[9];
  float* out = (float*)d_out;
  float* ws = (float*)d_ws;

  mega_kernel<<<NBLK, 256, 0, stream>>>(coefs, preds, nodes, cloud, cls,
                                        pjl, pja, gjl, gja, gps, ws, out);
  final1_kernel<<<2 * NB, 256, 0, stream>>>(nodes, ws, out);
}